// Round 6
// baseline (594.017 us; speedup 1.0000x reference)
//
#include <hip/hip_runtime.h>
#include <math.h>

#define N_NODES 32768
#define F 128
#define KD 64

typedef short  s8v  __attribute__((ext_vector_type(8)));   // 8 x bf16 (bit pattern)
typedef float  f4v  __attribute__((ext_vector_type(4)));   // MFMA accumulator
typedef unsigned short u16;

__device__ __forceinline__ float ssp(float a) {
    return fmaxf(a, 0.0f) + log1pf(expf(-fabsf(a))) - 0.69314718055994531f;
}
__device__ __forceinline__ u16 f2b(float f) {               // fp32 -> bf16 RNE
    unsigned int u = __builtin_bit_cast(unsigned int, f);
    u += 0x7fffu + ((u >> 16) & 1u);
    return (u16)(u >> 16);
}
__device__ __forceinline__ float b2f(u16 h) {
    unsigned int u = ((unsigned int)h) << 16;
    return __builtin_bit_cast(float, u);
}

// Wave-level LDS fence (same-wave write->read ordering, no __syncthreads).
__device__ __forceinline__ void wfence() {
    asm volatile("s_waitcnt lgkmcnt(0)" ::: "memory");
    __builtin_amdgcn_wave_barrier();
    __builtin_amdgcn_sched_barrier(0);
}

// ---------------------------------------------------------------------------
// Per-wave MFMA GEMM: 16 rows x 128 cols x K=128.
// A in wave-private LDS [16][136] bf16; B direct from global bf16 weights
// (L1/L2-resident, shared by all waves). C/D: col=lane&15, row=(lane>>4)*4+reg.
// ---------------------------------------------------------------------------
__device__ __forceinline__ void gemm16(const u16* S, const u16* Wg,
                                       int m, int q, f4v acc[8])
{
    #pragma unroll
    for (int ct = 0; ct < 8; ++ct) acc[ct] = (f4v){0.f, 0.f, 0.f, 0.f};
    #pragma unroll
    for (int ks = 0; ks < 4; ++ks) {
        s8v a = *(const s8v*)&S[m * 136 + ks * 32 + q * 8];
        #pragma unroll
        for (int ct = 0; ct < 8; ++ct) {
            s8v b = *(const s8v*)&Wg[(ct * 16 + m) * 128 + ks * 32 + q * 8];
            acc[ct] = __builtin_amdgcn_mfma_f32_16x16x32_bf16(a, b, acc[ct], 0, 0, 0);
        }
    }
}

// Same, A-frags already in registers (a[ks] = A[m][ks*32+q*8 .. +7]).
__device__ __forceinline__ void gemm16_regA(const s8v a[4], const u16* Wg,
                                            int m, int q, f4v acc[8])
{
    #pragma unroll
    for (int ct = 0; ct < 8; ++ct) acc[ct] = (f4v){0.f, 0.f, 0.f, 0.f};
    #pragma unroll
    for (int ks = 0; ks < 4; ++ks) {
        #pragma unroll
        for (int ct = 0; ct < 8; ++ct) {
            s8v b = *(const s8v*)&Wg[(ct * 16 + m) * 128 + ks * 32 + q * 8];
            acc[ct] = __builtin_amdgcn_mfma_f32_16x16x32_bf16(a[ks], b, acc[ct], 0, 0, 0);
        }
    }
}

// C-layout -> A-layout restage into wave-private LDS [16][136].
__device__ __forceinline__ void writeA16(u16* S, int q, int m, const float v[8][4])
{
    #pragma unroll
    for (int ct = 0; ct < 8; ++ct) {
        int c = ct * 16 + m;
        #pragma unroll
        for (int reg = 0; reg < 4; ++reg)
            S[(q * 4 + reg) * 136 + c] = f2b(v[ct][reg]);
    }
}

// ---------------------------------------------------------------------------
// prep: fp32 -> bf16 for weights + k2f.
// ---------------------------------------------------------------------------
__global__ __launch_bounds__(256)
void prep_kernel(const float* __restrict__ wi, const float* __restrict__ wj,
                 const float* __restrict__ rw1, const float* __restrict__ rw2,
                 const float* __restrict__ wd, const float* __restrict__ k2f,
                 u16* __restrict__ WB, u16* __restrict__ K2FB)
{
    int b = blockIdx.x, t = threadIdx.x;
    const float* src; u16* dst; int off;
    if (b < 112) {
        int seg = b >> 4; off = (b & 15) * 1024 + t * 4;
        const float* srcs[7] = {wi, wj, rw1, rw2, rw1 + 16384, rw2 + 16384, wd};
        src = srcs[seg]; dst = WB + seg * 16384;
    } else {
        off = (b - 112) * 1024 + t * 4;
        src = k2f; dst = K2FB;
    }
    float4 v = *(const float4*)(src + off);
    ushort4 h; h.x = f2b(v.x); h.y = f2b(v.y); h.z = f2b(v.z); h.w = f2b(v.w);
    *(ushort4*)(dst + off) = h;
}

// ---------------------------------------------------------------------------
// in v6: 64-thread (1-wave) blocks, grid 2048, ZERO LDS, ZERO barriers.
// Each wave owns 16 rows: A-frags per-lane from global w/ in-register ssp
// (R3-proven), both GEMMs share them. xi fp32 64B-segment stores; xv bf16
// scalar C-layout stores (32B segments; 8.4 MB total - cheap, and removes
// the LDS restage that coupled occupancy to LDS in R3).
// (64,4): 4 waves/SIMD -> 128 VGPR budget; need ~80. Up to 16 wg/CU,
// 8 pipelined rounds over the grid.
// ---------------------------------------------------------------------------
__global__ __launch_bounds__(64, 4)
void in_kernel(const float* __restrict__ x, const u16* __restrict__ WB,
               const float* __restrict__ bi, const float* __restrict__ bj,
               float* __restrict__ xi_out, u16* __restrict__ xv_out)
{
    const int lane = threadIdx.x, m = lane & 15, q = lane >> 4;
    const int row0 = blockIdx.x * 16;

    // A-frags: lane(m,q) holds A[row0+m][ks*32+q*8 .. +7] = bf16(ssp(x))
    s8v a[4];
    const float* xr = x + (size_t)(row0 + m) * F + q * 8;
    #pragma unroll
    for (int ks = 0; ks < 4; ++ks) {
        float4 v0 = *(const float4*)(xr + ks * 32);
        float4 v1 = *(const float4*)(xr + ks * 32 + 4);
        a[ks][0] = (short)f2b(ssp(v0.x)); a[ks][1] = (short)f2b(ssp(v0.y));
        a[ks][2] = (short)f2b(ssp(v0.z)); a[ks][3] = (short)f2b(ssp(v0.w));
        a[ks][4] = (short)f2b(ssp(v1.x)); a[ks][5] = (short)f2b(ssp(v1.y));
        a[ks][6] = (short)f2b(ssp(v1.z)); a[ks][7] = (short)f2b(ssp(v1.w));
    }

    f4v acc[8];
    // ---- GEMM wi -> xi (fp32, 64B-segment stores)
    gemm16_regA(a, WB + 0 * 16384, m, q, acc);
    #pragma unroll
    for (int ct = 0; ct < 8; ++ct) {
        int c = ct * 16 + m; float bv = bi[c];
        #pragma unroll
        for (int reg = 0; reg < 4; ++reg)
            xi_out[(size_t)(row0 + q * 4 + reg) * F + c] = acc[ct][reg] + bv;
    }
    // ---- GEMM wj -> xv (bf16, scalar C-layout stores)
    gemm16_regA(a, WB + 1 * 16384, m, q, acc);
    #pragma unroll
    for (int ct = 0; ct < 8; ++ct) {
        int c = ct * 16 + m; float bv = bj[c];
        #pragma unroll
        for (int reg = 0; reg < 4; ++reg)
            xv_out[(size_t)(row0 + q * 4 + reg) * F + c] = f2b(acc[ct][reg] + bv);
    }
}

// ---------------------------------------------------------------------------
// attn v5 (UNCHANGED from round 5 — control): xj lives in fp32 MFMA
// accumulators its whole life; 187us invariant under VALU-halving (R5),
// occupancy changes (R1/R2), and restructuring (R3) — held fixed while
// this round targets in/tail.
// ---------------------------------------------------------------------------
__global__ __launch_bounds__(256, 4)
void attn_kernel(const float* __restrict__ xi_in, const u16* __restrict__ xvb,
                 const float* __restrict__ rbf, const int* __restrict__ idx_j,
                 const u16* __restrict__ k2fb, float* __restrict__ m_out)
{
    __shared__ u16   xv_s[64 * 136];     // 17408 B, row = block-edge
    __shared__ float slog[4][32];        // per-wave logit partials
    __shared__ float att_s[64];          // [node-local 2][32]
    __shared__ float comb[4][128];       // per-wave combine partials

    const int t = threadIdx.x, w = t >> 6, lane = t & 63;
    const int m = lane & 15, q = lane >> 4;
    const size_t e0 = (size_t)blockIdx.x * 64;
    const int n0 = blockIdx.x * 2;
    const int nw = n0 + (w >> 1);        // node this wave's edges belong to

    // ---- gather xv[idx_j] -> LDS rows (wave-private: writer wave == reader)
    {
        const int e_my = t >> 2, coff = (t & 3) * 32;
        const int jj = idx_j[e0 + e_my];
        const u16* xvp = xvb + (size_t)jj * F + coff;
        #pragma unroll
        for (int i = 0; i < 4; ++i)
            *(s8v*)&xv_s[e_my * 136 + coff + i * 8] = *(const s8v*)(xvp + i * 8);
    }

    // ---- g-GEMM: 16 edges/wave x 128 cols x K=64 -> acc (fp32, C-layout)
    f4v acc[8];
    #pragma unroll
    for (int ct = 0; ct < 8; ++ct) acc[ct] = (f4v){0.f, 0.f, 0.f, 0.f};
    {
        const float* arow = rbf + (e0 + (size_t)(w * 16 + m)) * KD;
        #pragma unroll
        for (int ks = 0; ks < 2; ++ks) {
            float4 a0 = *(const float4*)(arow + ks * 32 + q * 8);
            float4 a1 = *(const float4*)(arow + ks * 32 + q * 8 + 4);
            s8v a;
            a[0] = (short)f2b(a0.x); a[1] = (short)f2b(a0.y);
            a[2] = (short)f2b(a0.z); a[3] = (short)f2b(a0.w);
            a[4] = (short)f2b(a1.x); a[5] = (short)f2b(a1.y);
            a[6] = (short)f2b(a1.z); a[7] = (short)f2b(a1.w);
            #pragma unroll
            for (int ct = 0; ct < 8; ++ct) {
                s8v b = *(const s8v*)&k2fb[(ct * 16 + m) * KD + ks * 32 + q * 8];
                acc[ct] = __builtin_amdgcn_mfma_f32_16x16x32_bf16(a, b, acc[ct], 0, 0, 0);
            }
        }
    }

    // ---- xi fragments for logits: xi4[reg] = xi[nw][me(reg)*4 .. +3]
    float4 xi4[4];
    #pragma unroll
    for (int reg = 0; reg < 4; ++reg) {
        int me = (w & 1) * 16 + q * 4 + reg;
        xi4[reg] = *(const float4*)(xi_in + (size_t)nw * F + me * 4);
    }

    wfence();   // xv_s writes (this wave) -> reads below

    // ---- acc *= xv (transpose read from wave-private rows)
    #pragma unroll
    for (int ct = 0; ct < 8; ++ct) {
        int c = ct * 16 + m;
        #pragma unroll
        for (int reg = 0; reg < 4; ++reg)
            acc[ct][reg] *= b2f(xv_s[(w * 16 + q * 4 + reg) * 136 + c]);
    }

    // ---- logits in-register: pE -> logit[nw][m], pO -> logit[nw][16+m]
    float pE = 0.f, pO = 0.f;
    #pragma unroll
    for (int reg = 0; reg < 4; ++reg) {
        float xf[4] = {xi4[reg].x, xi4[reg].y, xi4[reg].z, xi4[reg].w};
        #pragma unroll
        for (int j = 0; j < 4; ++j) {
            pE = fmaf(xf[j], acc[2 * j][reg], pE);
            pO = fmaf(xf[j], acc[2 * j + 1][reg], pO);
        }
    }
    pE += __shfl_xor(pE, 16); pE += __shfl_xor(pE, 32);
    pO += __shfl_xor(pO, 16); pO += __shfl_xor(pO, 32);
    if (lane < 16) { slog[w][m] = pE; slog[w][16 + m] = pO; }
    __syncthreads();

    // ---- softmax (node nn's 32 logits = slog[2nn] + slog[2nn+1])
    if (t < 64) {
        const int nn = t >> 5, mm = t & 31;
        float s = slog[2 * nn][mm] + slog[2 * nn + 1][mm];
        float mx = s;
        #pragma unroll
        for (int o = 16; o; o >>= 1) mx = fmaxf(mx, __shfl_xor(mx, o));
        float ex = expf(s - mx);
        float sum = ex;
        #pragma unroll
        for (int o = 16; o; o >>= 1) sum += __shfl_xor(sum, o);
        att_s[nn * 32 + mm] = ex / sum;
    }
    __syncthreads();

    // ---- combine: part[ct] = sum_reg att[me(reg)] * acc[ct][reg]
    float part[8];
    {
        float av[4];
        #pragma unroll
        for (int reg = 0; reg < 4; ++reg)
            av[reg] = att_s[w * 16 + q * 4 + reg];   // broadcast across m-lanes
        #pragma unroll
        for (int ct = 0; ct < 8; ++ct) {
            float p = 0.f;
            #pragma unroll
            for (int reg = 0; reg < 4; ++reg) p = fmaf(av[reg], acc[ct][reg], p);
            p += __shfl_xor(p, 16); p += __shfl_xor(p, 32);
            part[ct] = p;
        }
    }
    if (lane < 16) {
        #pragma unroll
        for (int ct = 0; ct < 8; ++ct) comb[w][ct * 16 + m] = part[ct];
    }
    __syncthreads();

    // ---- final: m[n][f] = xi[n][f] + comb[2nn][f] + comb[2nn+1][f]
    {
        const int nn = t >> 7, f = t & 127;
        float v = xi_in[(size_t)(n0 + nn) * F + f]
                + comb[2 * nn][f] + comb[2 * nn + 1][f];
        m_out[(size_t)(n0 + nn) * F + f] = v;
    }
}

// ---------------------------------------------------------------------------
// tail v6: 64-thread (1-wave) blocks, grid 2048, ZERO __syncthreads.
// Wave-private 4.4 KB LDS tile chains the 5 GEMMs (C->A restage, wfence-
// ordered — functionally proven in R3; R3's slowness was its 69.6 KB/block
// LDS capping occupancy at 2 blocks/CU). Now 16 wg/CU, 8 pipelined rounds.
// (64,4): 128 VGPR budget; need ~100.
// ---------------------------------------------------------------------------
__global__ __launch_bounds__(64, 4)
void tail_kernel(const float* __restrict__ m_in, const float* __restrict__ x,
                 const float* __restrict__ u, const u16* __restrict__ WB,
                 const float* __restrict__ rb1, const float* __restrict__ rb2,
                 const float* __restrict__ bd, float* __restrict__ out)
{
    __shared__ u16 S[16 * 136];          // 4352 B
    const int lane = threadIdx.x, m = lane & 15, q = lane >> 4;
    const int row0 = blockIdx.x * 16;
    const int rbase = row0 + q * 4;

    float cur[8][4], tmp[8][4];
    #pragma unroll
    for (int ct = 0; ct < 8; ++ct) {
        int c = ct * 16 + m;
        #pragma unroll
        for (int reg = 0; reg < 4; ++reg)
            cur[ct][reg] = m_in[(size_t)(rbase + reg) * F + c];
    }

    f4v acc[8];
    #pragma unroll 1
    for (int r = 0; r < 2; ++r) {
        #pragma unroll
        for (int ct = 0; ct < 8; ++ct)
            #pragma unroll
            for (int reg = 0; reg < 4; ++reg) tmp[ct][reg] = ssp(cur[ct][reg]);
        writeA16(S, q, m, tmp);
        wfence();
        gemm16(S, WB + (2 + 2 * r) * 16384, m, q, acc);     // rw1_r
        wfence();                                           // reads done before rewrite
        #pragma unroll
        for (int ct = 0; ct < 8; ++ct) {
            float bv = rb1[r * F + ct * 16 + m];
            #pragma unroll
            for (int reg = 0; reg < 4; ++reg) tmp[ct][reg] = acc[ct][reg] + bv;
        }
        writeA16(S, q, m, tmp);
        wfence();
        gemm16(S, WB + (3 + 2 * r) * 16384, m, q, acc);     // rw2_r
        #pragma unroll
        for (int ct = 0; ct < 8; ++ct) {
            float bv = rb2[r * F + ct * 16 + m];
            #pragma unroll
            for (int reg = 0; reg < 4; ++reg) cur[ct][reg] += acc[ct][reg] + bv;
        }
        wfence();                                           // reads done before rewrite
    }

    #pragma unroll
    for (int ct = 0; ct < 8; ++ct)
        #pragma unroll
        for (int reg = 0; reg < 4; ++reg) tmp[ct][reg] = ssp(cur[ct][reg]);
    writeA16(S, q, m, tmp);
    wfence();
    gemm16(S, WB + 6 * 16384, m, q, acc);                   // wd
    #pragma unroll
    for (int ct = 0; ct < 8; ++ct) {
        int c = ct * 16 + m;
        float uv = u[c], bv = bd[c];
        #pragma unroll
        for (int reg = 0; reg < 4; ++reg) {
            size_t r = (size_t)(rbase + reg) * F + c;
            out[r] = fmaf(uv, x[r], acc[ct][reg] + bv);
        }
    }
}

// ---------------------------------------------------------------------------
extern "C" void kernel_launch(void* const* d_in, const int* in_sizes, int n_in,
                              void* d_out, int out_size, void* d_ws, size_t ws_size,
                              hipStream_t stream)
{
    const float* x     = (const float*)d_in[0];
    const float* rbf   = (const float*)d_in[1];
    const int*   idx_j = (const int*)d_in[3];   // idx_i (d_in[2]) unused by ref
    const float* k2f_w = (const float*)d_in[4];
    const float* wi    = (const float*)d_in[5];
    const float* bi    = (const float*)d_in[6];
    const float* wj    = (const float*)d_in[7];
    const float* bj    = (const float*)d_in[8];
    const float* rw1   = (const float*)d_in[9];
    const float* rb1   = (const float*)d_in[10];
    const float* rw2   = (const float*)d_in[11];
    const float* rb2   = (const float*)d_in[12];
    const float* wd    = (const float*)d_in[13];
    const float* bd    = (const float*)d_in[14];
    const float* u     = (const float*)d_in[15];
    float* out = (float*)d_out;

    const size_t NF = (size_t)N_NODES * F;
    float* B0   = (float*)d_ws;          // xi, then m (attn writes in place)
    u16*   XVB  = (u16*)(B0 + NF);       // xv bf16
    u16*   WB   = XVB + NF;              // 7 x [128][128] bf16 weights
    u16*   K2FB = WB + 7 * 16384;        // [128][64] bf16

    hipLaunchKernelGGL(prep_kernel, dim3(120), dim3(256), 0, stream,
                       wi, wj, rw1, rw2, wd, k2f_w, WB, K2FB);

    hipLaunchKernelGGL(in_kernel, dim3(N_NODES / 16), dim3(64), 0, stream,
                       x, WB, bi, bj, B0, XVB);

    hipLaunchKernelGGL(attn_kernel, dim3(N_NODES / 2), dim3(256), 0, stream,
                       B0, XVB, rbf, idx_j, K2FB, B0);

    hipLaunchKernelGGL(tail_kernel, dim3(N_NODES / 16), dim3(64), 0, stream,
                       B0, x, u, WB, rb1, rb2, bd, out);
}